// Round 25
// baseline (200.858 us; speedup 1.0000x reference)
//
#include <hip/hip_runtime.h>

#define N_NODES 100000
#define IN_DIM 64
#define EMB 128
#define N_EDGES 1600000
#define BN_EPS 1e-5f

// bucket partition
#define NB 98
#define BCAP 18432
#define FA_THREADS 512
#define FA_EPT 16
#define FA_BLK (FA_THREADS * FA_EPT)
#define FA_GRID ((N_EDGES + FA_BLK - 1) / FA_BLK)   // 196

// ---- workspace layout (bytes) ----
#define WS_GSUM     0
#define WS_GSUM2    512
#define WS_BCUR     1024
#define WS_ROWSTART 2048
#define WS_PAIRS    802304                  // 12.8 MB
#define WS_H16      13602304                // 25.6 MB region (h16 uses half)
#define WS_DSTARR   39202304                // 7.2 MB (dead after fillB2 -> x16 overlay)
#define WS_SWARR    46427648                // 14.5 MB (dead after fillB2)
#define WS_X16      WS_DSTARR
#define WS_ZERO_INTS 512

typedef _Float16 half8_t __attribute__((ext_vector_type(8)));
typedef _Float16 half4_t __attribute__((ext_vector_type(4)));
typedef _Float16 half2_t __attribute__((ext_vector_type(2)));
typedef float floatx4 __attribute__((ext_vector_type(4)));

// ---------------- zero: replaces hipMemsetAsync -----------------------------
__global__ __launch_bounds__(512) void zero_kernel(int* __restrict__ p)
{
    p[threadIdx.x] = 0;
}

// ---------------- fillA: partition edges into 98 dst-buckets ----------------
__global__ __launch_bounds__(512) void fillA_kernel(
    const int* __restrict__ ei, const float* __restrict__ ew,
    int* __restrict__ bcur, int* __restrict__ dstArr, float2* __restrict__ swArr)
{
    __shared__ int cnt[NB], base[NB];
    const int tid = threadIdx.x;
    if (tid < NB) cnt[tid] = 0;
    __syncthreads();
    const int e0 = blockIdx.x * FA_BLK;
    int pk[FA_EPT];
    #pragma unroll
    for (int i = 0; i < FA_EPT; ++i) {
        int e = e0 + i * FA_THREADS + tid;
        pk[i] = -1;
        if (e < N_EDGES) {
            int d = ei[N_EDGES + e];
            int b = d >> 10;
            int pos = atomicAdd(&cnt[b], 1);   // LDS atomic
            pk[i] = (b << 13) | pos;
        }
    }
    __syncthreads();
    if (tid < NB) base[tid] = atomicAdd(&bcur[tid], cnt[tid]);
    __syncthreads();
    #pragma unroll
    for (int i = 0; i < FA_EPT; ++i) {
        int e = e0 + i * FA_THREADS + tid;
        if (pk[i] >= 0) {
            int b = pk[i] >> 13, pos = pk[i] & 8191;
            int idx = b * BCAP + base[b] + pos;
            dstArr[idx] = ei[N_EDGES + e];
            swArr[idx]  = make_float2(__int_as_float(ei[e]), ew[e]);
        }
    }
}

// ---------------- fillB2: hist + scan + rowstart + scatter ------------------
__global__ __launch_bounds__(1024) void fillB2_kernel(
    const int* __restrict__ bcur, const int* __restrict__ dstArr,
    const float2* __restrict__ swArr,
    int* __restrict__ rowstart, float2* __restrict__ pairs)
{
    __shared__ int cnt2[1024];
    __shared__ int pre[1024];
    __shared__ int sbk[128];
    const int g = blockIdx.x;
    const int tid = threadIdx.x;

    if (tid < 128) sbk[tid] = (tid < NB) ? bcur[tid] : 0;
    cnt2[tid] = 0;
    __syncthreads();
    for (int off = 1; off < 128; off <<= 1) {
        int v = 0;
        if (tid < 128 && tid >= off) v = sbk[tid - off];
        __syncthreads();
        if (tid < 128) sbk[tid] += v;
        __syncthreads();
    }
    const int bucketBase = (g > 0) ? sbk[g - 1] : 0;

    const int nE = bcur[g];
    const int segBase = g * BCAP;
    for (int j = tid; j < nE; j += 1024)
        atomicAdd(&cnt2[dstArr[segBase + j] & 1023], 1);
    __syncthreads();

    const int c = cnt2[tid];
    pre[tid] = c;
    __syncthreads();
    for (int off = 1; off < 1024; off <<= 1) {
        int v = (tid >= off) ? pre[tid - off] : 0;
        __syncthreads();
        pre[tid] += v;
        __syncthreads();
    }
    const int start = bucketBase + pre[tid] - c;
    const int node = g * 1024 + tid;
    if (node < N_NODES) rowstart[node] = start;
    if (node == N_NODES - 1) rowstart[N_NODES] = start + c;

    __syncthreads();
    cnt2[tid] = start;
    __syncthreads();
    #pragma unroll 4
    for (int j = tid; j < nE; j += 1024) {
        int d = dstArr[segBase + j];
        int p = atomicAdd(&cnt2[d & 1023], 1);
        pairs[p] = swArr[segBase + j];
    }
}

// ---------------- cvt: x -> fp16 sidecar ------------------------------------
__global__ __launch_bounds__(256) void cvt_kernel(
    const float4* __restrict__ x4, ushort4* __restrict__ x16)
{
    int i = blockIdx.x * 256 + threadIdx.x;
    if (i >= N_NODES * IN_DIM / 4) return;
    float4 v = x4[i];
    ushort4 u;
    _Float16 a = (_Float16)v.x, b = (_Float16)v.y,
             c = (_Float16)v.z, d = (_Float16)v.w;
    u.x = *(unsigned short*)&a; u.y = *(unsigned short*)&b;
    u.z = *(unsigned short*)&c; u.w = *(unsigned short*)&d;
    x16[i] = u;
}

// ---------------- fused gather + W1 GEMM + BN partials ----------------------
// r24: gemv pinned at ~44us (startup-bound, 4 variants). Fusion deletes it:
// block = 32 nodes (one MFMA M-tile); gather rows -> LDS fp16 A-tile; W1
// staged once/block (overlaps gather latency); 16-MFMA epilogue writes h16
// and BN partials in-block. Deletes agg round-trip (77 MB + launch).
#define GG_NPW 8   // nodes per wave -> 32/block -> 3125 blocks
__global__ __launch_bounds__(256) void gath_gemv_kernel(
    const _Float16* __restrict__ x16,
    const int* __restrict__ rowstart,
    const float2* __restrict__ pairs,
    const float* __restrict__ W1,   // [64,128] row-major, fp32
    const float* __restrict__ b1,
    _Float16* __restrict__ h16,     // [N,128] fp16
    float* __restrict__ gsum, float* __restrict__ gsum2)
{
    __shared__ _Float16 w1t[EMB][72];     // transposed W1 fp16 (18.4 KB)
    __shared__ _Float16 Ah[32][72];       // A-tile: 32 node-rows fp16 (4.6 KB)
    __shared__ float redS[4][EMB], redQ[4][EMB];   // 4 KB

    const int tid  = threadIdx.x;
    const int lane = tid & 63;
    const int wid  = tid >> 6;
    const int e    = lane >> 4;     // edge slot 0..3
    const int f    = lane & 15;     // quad 0..15
    const int l15  = lane & 15;
    const int kb   = lane >> 4;
    const half4_t* __restrict__ xv4 = (const half4_t*)x16;
    const int node0 = blockIdx.x * 32;

    // zero BN partial arrays (read after barrier2; written after barrier1)
    #pragma unroll
    for (int i = 0; i < 2; ++i) {
        ((float*)redS)[i * 256 + tid] = 0.f;
        ((float*)redQ)[i * 256 + tid] = 0.f;
    }
    // stage W1 -> LDS fp16 transposed (independent of gather; latency overlaps)
    #pragma unroll
    for (int i = 0; i < 32; ++i) {
        int idx = i * 256 + tid;
        w1t[idx & 127][idx >> 7] = (_Float16)W1[idx];
    }

    // ---- gather phase: each wave computes 8 node-rows into Ah ----
    for (int r = 0; r < GG_NPW; ++r) {
        const int n  = node0 + wid * GG_NPW + r;
        const int jb = rowstart[n];
        const int je = rowstart[n + 1];
        float4 accA = make_float4(0.f, 0.f, 0.f, 0.f);
        float4 accB = make_float4(0.f, 0.f, 0.f, 0.f);
        for (int j0 = jb; j0 < je; j0 += 64) {
            const int cnt = min(64, je - j0);
            float2 p = (lane < cnt) ? pairs[j0 + lane] : make_float2(0.f, 0.f);
            int   psrc = __float_as_int(p.x);
            float pw   = p.y;
            const int nch = (cnt + 7) >> 3;
            #pragma unroll 4
            for (int c = 0; c < nch; ++c) {
                int   uA = __shfl(psrc, c * 8 + e);
                float wA = __shfl(pw,   c * 8 + e);
                int   uB = __shfl(psrc, c * 8 + 4 + e);
                float wB = __shfl(pw,   c * 8 + 4 + e);
                half4_t va = xv4[(size_t)(unsigned)uA * 16 + f];
                half4_t vb = xv4[(size_t)(unsigned)uB * 16 + f];
                accA.x += wA * (float)va[0]; accA.y += wA * (float)va[1];
                accA.z += wA * (float)va[2]; accA.w += wA * (float)va[3];
                accB.x += wB * (float)vb[0]; accB.y += wB * (float)vb[1];
                accB.z += wB * (float)vb[2]; accB.w += wB * (float)vb[3];
            }
        }
        float4 s = make_float4(accA.x + accB.x, accA.y + accB.y,
                               accA.z + accB.z, accA.w + accB.w);
        s.x += __shfl_xor(s.x, 16); s.y += __shfl_xor(s.y, 16);
        s.z += __shfl_xor(s.z, 16); s.w += __shfl_xor(s.w, 16);
        s.x += __shfl_xor(s.x, 32); s.y += __shfl_xor(s.y, 32);
        s.z += __shfl_xor(s.z, 32); s.w += __shfl_xor(s.w, 32);
        if (e == 0) {   // lanes 0-15: add self term, store row as fp16
            half4_t sv = xv4[(size_t)n * 16 + f];
            half4_t hrow;
            hrow[0] = (_Float16)(s.x + (float)sv[0]);
            hrow[1] = (_Float16)(s.y + (float)sv[1]);
            hrow[2] = (_Float16)(s.z + (float)sv[2]);
            hrow[3] = (_Float16)(s.w + (float)sv[3]);
            *(half4_t*)&Ah[wid * GG_NPW + r][f * 4] = hrow;
        }
    }
    __syncthreads();   // Ah + w1t + redS-zero complete

    // ---- MFMA phase: wave (rg,ch) does 16 rows x 64 cols ----
    const int rg  = wid >> 1;
    const int ch  = wid & 1;
    const int c0w = ch * 64;

    half8_t Bf[4][2];
    #pragma unroll
    for (int ct = 0; ct < 4; ++ct)
        #pragma unroll
        for (int kc = 0; kc < 2; ++kc)
            Bf[ct][kc] = *(half8_t*)&w1t[c0w + ct * 16 + l15][kc * 32 + kb * 8];
    float b1c[4];
    #pragma unroll
    for (int ct = 0; ct < 4; ++ct) b1c[ct] = b1[c0w + ct * 16 + l15];

    half8_t af[2];
    #pragma unroll
    for (int kc = 0; kc < 2; ++kc)
        af[kc] = *(half8_t*)&Ah[rg * 16 + l15][kc * 32 + kb * 8];

    floatx4 acc[4];
    #pragma unroll
    for (int ct = 0; ct < 4; ++ct)
        acc[ct] = (floatx4){b1c[ct], b1c[ct], b1c[ct], b1c[ct]};
    #pragma unroll
    for (int kc = 0; kc < 2; ++kc)
        #pragma unroll
        for (int ct = 0; ct < 4; ++ct)
            acc[ct] = __builtin_amdgcn_mfma_f32_16x16x32_f16(af[kc], Bf[ct][kc], acc[ct], 0, 0, 0);

    float sA[4] = {0, 0, 0, 0}, qA[4] = {0, 0, 0, 0};
    #pragma unroll
    for (int ct = 0; ct < 4; ++ct) {
        #pragma unroll
        for (int i = 0; i < 4; ++i) {
            const int r = node0 + rg * 16 + kb * 4 + i;
            const float v = acc[ct][i];
            h16[(size_t)r * EMB + c0w + ct * 16 + l15] = (_Float16)v;
            sA[ct] += v;
            qA[ct] += v * v;
        }
    }
    #pragma unroll
    for (int ct = 0; ct < 4; ++ct) {
        sA[ct] += __shfl_xor(sA[ct], 16); sA[ct] += __shfl_xor(sA[ct], 32);
        qA[ct] += __shfl_xor(qA[ct], 16); qA[ct] += __shfl_xor(qA[ct], 32);
    }
    if (lane < 16) {
        #pragma unroll
        for (int ct = 0; ct < 4; ++ct) {
            redS[wid][c0w + ct * 16 + lane] = sA[ct];
            redQ[wid][c0w + ct * 16 + lane] = qA[ct];
        }
    }
    __syncthreads();
    if (tid < EMB) {
        float s = redS[0][tid] + redS[1][tid] + redS[2][tid] + redS[3][tid];
        float q = redQ[0][tid] + redQ[1][tid] + redQ[2][tid] + redQ[3][tid];
        atomicAdd(&gsum[tid],  s);
        atomicAdd(&gsum2[tid], q);
    }
}

// ---------------- mlp2: out = relu(BN(h16)) @ W2 + b2 (fp16 in, fp32 out) ---
#define MR 32
#define M2_ITERS 5
#define M2_ROWS (MR * M2_ITERS)   // 160 rows/block -> 625 blocks

__global__ __launch_bounds__(256) void mlp2_kernel(
    const _Float16* __restrict__ h16,
    float* __restrict__ out,
    const float* __restrict__ gsum, const float* __restrict__ gsum2,
    const float* __restrict__ gamma, const float* __restrict__ beta,
    const float* __restrict__ W2,   // [128,128] row-major, fp32
    const float* __restrict__ b2)
{
    __shared__ _Float16 Ph[MR][136];
    __shared__ float abuf[EMB], bbuf[EMB];

    const int tid  = threadIdx.x;
    const int lane = tid & 63;
    const int wid  = tid >> 6;
    const int rg   = wid >> 1;
    const int ch   = wid & 1;
    const int c0w  = ch * 64;
    const int l15  = lane & 15;
    const int kb   = lane >> 4;

    if (tid < EMB) {
        const float invN = 1.0f / (float)N_NODES;
        float mean = gsum[tid] * invN;
        float var  = gsum2[tid] * invN - mean * mean;
        float inv  = rsqrtf(var + BN_EPS);
        float a    = gamma[tid] * inv;
        abuf[tid] = a;
        bbuf[tid] = beta[tid] - mean * a;
    }

    const int bcol = c0w + l15;
    half8_t Bf[4][4];
    #pragma unroll
    for (int ct = 0; ct < 4; ++ct) {
        #pragma unroll
        for (int kc = 0; kc < 4; ++kc) {
            #pragma unroll
            for (int i = 0; i < 8; ++i)
                Bf[ct][kc][i] = (_Float16)W2[(kc * 32 + kb * 8 + i) * EMB + ct * 16 + bcol];
        }
    }
    float b2c[4];
    #pragma unroll
    for (int ct = 0; ct < 4; ++ct) b2c[ct] = b2[ct * 16 + bcol];

    __syncthreads();

    const int r0blk = blockIdx.x * M2_ROWS;
    for (int it = 0; it < M2_ITERS; ++it) {
        const int r0 = r0blk + it * MR;
        #pragma unroll
        for (int i = 0; i < 8; ++i) {
            int j   = i * 256 + tid;
            int row = j >> 6;
            int c2  = (j & 63) * 2;
            half2_t hv = *(const half2_t*)&h16[(size_t)(r0 + row) * EMB + c2];
            float p0 = fmaxf((float)hv[0] * abuf[c2]     + bbuf[c2],     0.f);
            float p1 = fmaxf((float)hv[1] * abuf[c2 + 1] + bbuf[c2 + 1], 0.f);
            Ph[row][c2]     = (_Float16)p0;
            Ph[row][c2 + 1] = (_Float16)p1;
        }
        __syncthreads();

        floatx4 acc[4];
        #pragma unroll
        for (int ct = 0; ct < 4; ++ct)
            acc[ct] = (floatx4){b2c[ct], b2c[ct], b2c[ct], b2c[ct]};
        #pragma unroll
        for (int kc = 0; kc < 4; ++kc) {
            half8_t af = *(half8_t*)&Ph[rg * 16 + l15][kc * 32 + kb * 8];
            #pragma unroll
            for (int ct = 0; ct < 4; ++ct)
                acc[ct] = __builtin_amdgcn_mfma_f32_16x16x32_f16(af, Bf[ct][kc], acc[ct], 0, 0, 0);
        }
        __syncthreads();

        #pragma unroll
        for (int ct = 0; ct < 4; ++ct) {
            #pragma unroll
            for (int i = 0; i < 4; ++i) {
                int row = r0 + rg * 16 + kb * 4 + i;
                out[(size_t)row * EMB + c0w + ct * 16 + l15] = acc[ct][i];
            }
        }
    }
}

extern "C" void kernel_launch(void* const* d_in, const int* in_sizes, int n_in,
                              void* d_out, int out_size, void* d_ws, size_t ws_size,
                              hipStream_t stream)
{
    const float* x     = (const float*)d_in[0];
    const int*   ei    = (const int*)d_in[1];   // int32 [2,E]
    const float* ew    = (const float*)d_in[3];
    const float* W1    = (const float*)d_in[4];
    const float* b1    = (const float*)d_in[5];
    const float* gamma = (const float*)d_in[6];
    const float* beta  = (const float*)d_in[7];
    const float* W2    = (const float*)d_in[8];
    const float* b2    = (const float*)d_in[9];

    char* ws = (char*)d_ws;
    float*    gsum     = (float*)(ws + WS_GSUM);
    float*    gsum2    = (float*)(ws + WS_GSUM2);
    int*      bcur     = (int*)(ws + WS_BCUR);
    int*      rowstart = (int*)(ws + WS_ROWSTART);
    float2*   pairs    = (float2*)(ws + WS_PAIRS);
    _Float16* h16      = (_Float16*)(ws + WS_H16);
    int*      dstArr   = (int*)(ws + WS_DSTARR);
    float2*   swArr    = (float2*)(ws + WS_SWARR);
    _Float16* x16      = (_Float16*)(ws + WS_X16);
    float*    out      = (float*)d_out;

    zero_kernel<<<1, WS_ZERO_INTS, 0, stream>>>((int*)d_ws);
    fillA_kernel<<<FA_GRID, FA_THREADS, 0, stream>>>(ei, ew, bcur, dstArr, swArr);
    fillB2_kernel<<<NB, 1024, 0, stream>>>(bcur, dstArr, swArr, rowstart, pairs);
    cvt_kernel<<<(N_NODES * IN_DIM / 4 + 255) / 256, 256, 0, stream>>>(
        (const float4*)x, (ushort4*)x16);
    gath_gemv_kernel<<<N_NODES / 32, 256, 0, stream>>>(
        x16, rowstart, pairs, W1, b1, h16, gsum, gsum2);
    mlp2_kernel<<<N_NODES / M2_ROWS, 256, 0, stream>>>(h16, out, gsum, gsum2, gamma, beta, W2, b2);
}